// Round 7
// baseline (195.104 us; speedup 1.0000x reference)
//
#include <hip/hip_runtime.h>
#include <hip/hip_bf16.h>
#include <math.h>

typedef _Float16 half8  __attribute__((ext_vector_type(8)));
typedef __fp16   fp16x2 __attribute__((ext_vector_type(2)));
typedef float    floatx4 __attribute__((ext_vector_type(4)));

#define IN_CH 64
#define HID   128
#define NSEG  4096

__device__ __forceinline__ unsigned fkey(float s) {
    unsigned u = __float_as_uint(s);
    return (u & 0x80000000u) ? ~u : (u | 0x80000000u);
}
__device__ __forceinline__ float funkey(unsigned k) {
    unsigned u = (k & 0x80000000u) ? (k ^ 0x80000000u) : ~k;
    return __uint_as_float(u);
}

// ---------------- init segment scratch ----------------
__global__ void init_seg(unsigned* __restrict__ segkey, float* __restrict__ denom) {
    int i = blockIdx.x * blockDim.x + threadIdx.x;
    if (i < NSEG) { segkey[i] = 0u; denom[i] = 0.0f; }
}

// ---------------- fused MLP -> scores ----------------
// Swapped-operand MFMA (R6, verified): A = w1 reg-resident, B = x-tile; lane
// owns one edge in D. NEW: x staged via global_load_lds into a per-wave
// depth-4 LDS ring with explicit counted vmcnt waits -> 3 tiles (12KB) always
// in flight per wave; no barriers (no cross-wave LDS sharing).
__global__ __launch_bounds__(256, 2) void mlp_score(
    const float* __restrict__ x, const float* __restrict__ w1,
    const float* __restrict__ b1, const float* __restrict__ w2,
    const float* __restrict__ b2, float* __restrict__ score, int E)
{
    // [wave][ring buf 0..3][instr 0..3][64 lanes * 16B]
    __shared__ __align__(16) char smem[4 * 4 * 4 * 1024];   // 64 KB

    const int tid  = threadIdx.x;
    const int lane = tid & 63;
    const int wid  = tid >> 6;
    const int g    = lane >> 4;   // 0..3
    const int l15  = lane & 15;   // 0..15

    // ---- one-time: w1 A-fragments (64 VGPRs), RTN cvt
    half8 afr[2][8];
#pragma unroll
    for (int ks = 0; ks < 2; ++ks)
#pragma unroll
        for (int ct = 0; ct < 8; ++ct) {
            const float* wp = w1 + (size_t)(ks * 32 + g * 8) * HID + ct * 16 + l15;
            half8 h;
#pragma unroll
            for (int j = 0; j < 8; ++j) h[j] = (_Float16)wp[(size_t)j * HID];
            afr[ks][ct] = h;
        }

    // ---- one-time: bias-as-C and w2 fragments
    floatx4 biasC[8], w2r[8];
#pragma unroll
    for (int ct = 0; ct < 8; ++ct)
#pragma unroll
        for (int r = 0; r < 4; ++r) {
            biasC[ct][r] = b1[ct * 16 + g * 4 + r];
            w2r[ct][r]   = w2[ct * 16 + g * 4 + r];
        }
    const float b2v = b2[0];

    const int nwtile = E >> 4;                  // 16-edge tiles
    const int TOTW   = (int)gridDim.x * 4;      // total waves
    const int gw     = blockIdx.x * 4 + wid;
    const int n      = nwtile / TOTW;           // tiles per wave (uniform part)
    const int rem    = nwtile - n * TOTW;

    char* lwave = smem + wid * 16384;
    const size_t laneoff = (size_t)l15 * IN_CH + g * 8;

    union H8 { half8 h8; fp16x2 h2[4]; };

#define STAGE(I) do {                                                          \
        int wt_ = gw + (I) * TOTW;                                             \
        const float* gs = x + (size_t)wt_ * (16 * IN_CH) + laneoff;            \
        char* lb = lwave + ((I) & 3) * 4096;                                   \
        __builtin_amdgcn_global_load_lds((const __attribute__((address_space(1))) void*)(gs),      (__attribute__((address_space(3))) void*)(lb),        16, 0, 0); \
        __builtin_amdgcn_global_load_lds((const __attribute__((address_space(1))) void*)(gs + 4),  (__attribute__((address_space(3))) void*)(lb + 1024), 16, 0, 0); \
        __builtin_amdgcn_global_load_lds((const __attribute__((address_space(1))) void*)(gs + 32), (__attribute__((address_space(3))) void*)(lb + 2048), 16, 0, 0); \
        __builtin_amdgcn_global_load_lds((const __attribute__((address_space(1))) void*)(gs + 36), (__attribute__((address_space(3))) void*)(lb + 3072), 16, 0, 0); \
    } while (0)

#define CORE(F0, F1, F2, F3, WT) do {                                          \
        H8 ub, uc;                                                             \
        ub.h2[0] = __builtin_amdgcn_cvt_pkrtz(F0[0], F0[1]);                   \
        ub.h2[1] = __builtin_amdgcn_cvt_pkrtz(F0[2], F0[3]);                   \
        ub.h2[2] = __builtin_amdgcn_cvt_pkrtz(F1[0], F1[1]);                   \
        ub.h2[3] = __builtin_amdgcn_cvt_pkrtz(F1[2], F1[3]);                   \
        uc.h2[0] = __builtin_amdgcn_cvt_pkrtz(F2[0], F2[1]);                   \
        uc.h2[1] = __builtin_amdgcn_cvt_pkrtz(F2[2], F2[3]);                   \
        uc.h2[2] = __builtin_amdgcn_cvt_pkrtz(F3[0], F3[1]);                   \
        uc.h2[3] = __builtin_amdgcn_cvt_pkrtz(F3[2], F3[3]);                   \
        floatx4 acc[8];                                                        \
        _Pragma("unroll")                                                      \
        for (int ct = 0; ct < 8; ++ct)                                         \
            acc[ct] = __builtin_amdgcn_mfma_f32_16x16x32_f16(afr[0][ct], ub.h8, biasC[ct], 0, 0, 0); \
        _Pragma("unroll")                                                      \
        for (int ct = 0; ct < 8; ++ct)                                         \
            acc[ct] = __builtin_amdgcn_mfma_f32_16x16x32_f16(afr[1][ct], uc.h8, acc[ct], 0, 0, 0);   \
        float s0 = 0.f, s1 = 0.f, s2 = 0.f, s3 = 0.f;                          \
        _Pragma("unroll")                                                      \
        for (int ct = 0; ct < 8; ++ct) {                                       \
            s0 += fmaxf(acc[ct][0], 0.f) * w2r[ct][0];                         \
            s1 += fmaxf(acc[ct][1], 0.f) * w2r[ct][1];                         \
            s2 += fmaxf(acc[ct][2], 0.f) * w2r[ct][2];                         \
            s3 += fmaxf(acc[ct][3], 0.f) * w2r[ct][3];                         \
        }                                                                      \
        float s = (s0 + s1) + (s2 + s3);                                       \
        s += __shfl_xor(s, 16);                                                \
        s += __shfl_xor(s, 32);                                                \
        if (lane < 16)                                                         \
            score[(size_t)(WT) * 16 + l15] = s + b2v;                          \
    } while (0)

#define BODY(I) do {                                                           \
        const char* lb = lwave + ((I) & 3) * 4096 + lane * 16;                 \
        floatx4 f0 = *(const floatx4*)(lb);                                    \
        floatx4 f1 = *(const floatx4*)(lb + 1024);                             \
        floatx4 f2 = *(const floatx4*)(lb + 2048);                             \
        floatx4 f3 = *(const floatx4*)(lb + 3072);                             \
        CORE(f0, f1, f2, f3, gw + (I) * TOTW);                                 \
        __builtin_amdgcn_sched_barrier(0);                                     \
    } while (0)

    if (n >= 4) {
        STAGE(0); STAGE(1); STAGE(2);
        int i = 0;
        for (; i < n - 3; ++i) {
            STAGE(i + 3);
            // 3 stages (12 loads) issued after stage(i): waiting to <=12
            // outstanding guarantees stage(i) retired (in-order retirement).
            asm volatile("s_waitcnt vmcnt(12)" ::: "memory");
            __builtin_amdgcn_sched_barrier(0);
            BODY(i);
        }
        asm volatile("s_waitcnt vmcnt(8)" ::: "memory");
        __builtin_amdgcn_sched_barrier(0);
        BODY(i); ++i;
        asm volatile("s_waitcnt vmcnt(4)" ::: "memory");
        __builtin_amdgcn_sched_barrier(0);
        BODY(i); ++i;
        asm volatile("s_waitcnt vmcnt(0)" ::: "memory");
        __builtin_amdgcn_sched_barrier(0);
        BODY(i);
    } else {
        for (int i = 0; i < n; ++i) {
            const float* xr = x + (size_t)(gw + i * TOTW) * (16 * IN_CH) + laneoff;
            floatx4 f0 = *(const floatx4*)(xr);
            floatx4 f1 = *(const floatx4*)(xr + 4);
            floatx4 f2 = *(const floatx4*)(xr + 32);
            floatx4 f3 = *(const floatx4*)(xr + 36);
            CORE(f0, f1, f2, f3, gw + i * TOTW);
        }
    }
    if (gw < rem) {   // remainder tiles (0 for E = 2^21)
        int wt_ = n * TOTW + gw;
        const float* xr = x + (size_t)wt_ * (16 * IN_CH) + laneoff;
        floatx4 f0 = *(const floatx4*)(xr);
        floatx4 f1 = *(const floatx4*)(xr + 4);
        floatx4 f2 = *(const floatx4*)(xr + 32);
        floatx4 f3 = *(const floatx4*)(xr + 36);
        CORE(f0, f1, f2, f3, wt_);
    }
#undef STAGE
#undef CORE
#undef BODY
}

// ---------------- segment max (run-compressed atomics) ----------------
__global__ __launch_bounds__(256) void seg_max(
    const float* __restrict__ score, const int* __restrict__ batch,
    unsigned* __restrict__ segkey, int E)
{
    int t = blockIdx.x * 256 + threadIdx.x;
    int i0 = t * 8;
    if (i0 + 8 > E) return;
    int4 bA = *(const int4*)(batch + i0);
    int4 bB = *(const int4*)(batch + i0 + 4);
    floatx4 sA = *(const floatx4*)(score + i0);
    floatx4 sB = *(const floatx4*)(score + i0 + 4);
    int   ids[8] = {bA.x, bA.y, bA.z, bA.w, bB.x, bB.y, bB.z, bB.w};
    float ss[8]  = {sA[0], sA[1], sA[2], sA[3], sB[0], sB[1], sB[2], sB[3]};
    int cur = ids[0];
    float m = ss[0];
#pragma unroll
    for (int j = 1; j < 8; ++j) {
        if (ids[j] == cur) {
            m = fmaxf(m, ss[j]);
        } else {
            atomicMax(segkey + cur, fkey(m));
            cur = ids[j];
            m = ss[j];
        }
    }
    atomicMax(segkey + cur, fkey(m));
}

// ---------------- segment denom (run-compressed atomics) ----------------
__global__ __launch_bounds__(256) void seg_denom(
    const float* __restrict__ score, const int* __restrict__ batch,
    const unsigned* __restrict__ segkey, float* __restrict__ denom, int E)
{
    int t = blockIdx.x * 256 + threadIdx.x;
    int i0 = t * 8;
    if (i0 + 8 > E) return;
    int4 bA = *(const int4*)(batch + i0);
    int4 bB = *(const int4*)(batch + i0 + 4);
    floatx4 sA = *(const floatx4*)(score + i0);
    floatx4 sB = *(const floatx4*)(score + i0 + 4);
    int   ids[8] = {bA.x, bA.y, bA.z, bA.w, bB.x, bB.y, bB.z, bB.w};
    float ss[8]  = {sA[0], sA[1], sA[2], sA[3], sB[0], sB[1], sB[2], sB[3]};
    int cur = ids[0];
    float m = funkey(segkey[cur]);
    float a = __expf(ss[0] - m);
#pragma unroll
    for (int j = 1; j < 8; ++j) {
        if (ids[j] == cur) {
            a += __expf(ss[j] - m);
        } else {
            atomicAdd(denom + cur, a);
            cur = ids[j];
            m = funkey(segkey[cur]);
            a = __expf(ss[j] - m);
        }
    }
    atomicAdd(denom + cur, a);
}

// ---------------- finalize: out = exp(s-m)/(denom+eps), in place ----------------
__global__ __launch_bounds__(256) void finalize(
    float* __restrict__ score, const int* __restrict__ batch,
    const unsigned* __restrict__ segkey, const float* __restrict__ denom, int E)
{
    int t = blockIdx.x * 256 + threadIdx.x;
    int i0 = t * 8;
    if (i0 + 8 > E) return;
    int4 bA = *(const int4*)(batch + i0);
    int4 bB = *(const int4*)(batch + i0 + 4);
    floatx4 sA = *(const floatx4*)(score + i0);
    floatx4 sB = *(const floatx4*)(score + i0 + 4);
    int   ids[8] = {bA.x, bA.y, bA.z, bA.w, bB.x, bB.y, bB.z, bB.w};
    float ss[8]  = {sA[0], sA[1], sA[2], sA[3], sB[0], sB[1], sB[2], sB[3]};
    floatx4 oA, oB;
#pragma unroll
    for (int j = 0; j < 4; ++j) {
        float mj = funkey(segkey[ids[j]]);
        oA[j] = __expf(ss[j] - mj) / (denom[ids[j]] + 1e-16f);
    }
#pragma unroll
    for (int j = 0; j < 4; ++j) {
        float mj = funkey(segkey[ids[j + 4]]);
        oB[j] = __expf(ss[j + 4] - mj) / (denom[ids[j + 4]] + 1e-16f);
    }
    *(floatx4*)(score + i0)     = oA;
    *(floatx4*)(score + i0 + 4) = oB;
}

extern "C" void kernel_launch(void* const* d_in, const int* in_sizes, int n_in,
                              void* d_out, int out_size, void* d_ws, size_t ws_size,
                              hipStream_t stream) {
    const float* x   = (const float*)d_in[0];
    const float* w1  = (const float*)d_in[1];
    const float* b1  = (const float*)d_in[2];
    const float* w2  = (const float*)d_in[3];
    const float* b2  = (const float*)d_in[4];
    const int* batch = (const int*)d_in[5];
    float* out = (float*)d_out;
    const int E = in_sizes[5];

    unsigned* segkey = (unsigned*)d_ws;
    float*    denom  = (float*)((char*)d_ws + NSEG * sizeof(unsigned));

    init_seg<<<(NSEG + 255) / 256, 256, 0, stream>>>(segkey, denom);
    // scores are written into d_out (reused as scratch), finalized in place
    mlp_score<<<512, 256, 0, stream>>>(x, w1, b1, w2, b2, out, E);
    const int nthr = E / 8;
    seg_max   <<<nthr / 256, 256, 0, stream>>>(out, batch, segkey, E);
    seg_denom <<<nthr / 256, 256, 0, stream>>>(out, batch, segkey, denom, E);
    finalize  <<<nthr / 256, 256, 0, stream>>>(out, batch, segkey, denom, E);
}